// Round 1
// baseline (123.623 us; speedup 1.0000x reference)
//
#include <hip/hip_runtime.h>
#include <math.h>

#define B 8
#define T 128
#define NKEY 127   // t-1
#define KDIM 64    // Q_DIM == KV_DIM
#define NH 4       // heads
#define CH 256     // NH*KDIM output channels

typedef _Float16 half8 __attribute__((ext_vector_type(8)));  // 8 fp16 (4 VGPRs)
typedef float floatx4 __attribute__((ext_vector_type(4)));   // MFMA C/D

// tanh(x) = 1 - 2/(e^{2x}+1). Saturates correctly at +/-inf, no clamp needed.
__device__ __forceinline__ float fast_tanh(float x) {
    float e = __expf(2.f * x);
    float r = __builtin_amdgcn_rcpf(e + 1.f);
    return fmaf(-2.f, r, 1.f);
}

// 8x float -> fp16 RNE (v_cvt_f16_f32 default round mode). fp16 half-ulp
// 2^-11 on BOTH operands beats R8's bf16-RNE-A (2^-8) + exact-B: better
// accuracy at HALF the MFMA count and half the frag LDS.
__device__ __forceinline__ half8 cvt8(const float4& a, const float4& b) {
    half8 h;
    h[0] = (_Float16)a.x; h[1] = (_Float16)a.y;
    h[2] = (_Float16)a.z; h[3] = (_Float16)a.w;
    h[4] = (_Float16)b.x; h[5] = (_Float16)b.y;
    h[6] = (_Float16)b.z; h[7] = (_Float16)b.w;
    return h;
}

// R9: occupancy restructure. R8's grid (1024 x 4 waves = 4096 waves) caps the
// machine at 50%; counters showed 39% total pipe-busy => latency-bound.
// Split each (b,t) into TWO blocks by head-pair (softmax is per-head, so the
// pairs are fully independent): grid 2048 x 256 = 8192 waves = 100% capacity,
// and each wave's serial chain halves (2 jt-tiles, 64 Phase-B keys, half the
// qb/Phase-C dots). kv is staged twice per (b,t); the duplicate read is
// L3-resident (33 MB << 256 MB).
// Wave wid: h2 = wid&1 (head within pair), role = wid>>1
//   scores : wave handles j-half role*32..+31 for ALL 8 n-tiles (partials
//            summed across the wave pair through pp_lds)
//   Phase B: wave handles n-half role*64..+63
// LDS 18944 B -> 8 blocks/CU; launch_bounds(256,4) caps VGPR at 64
// (empirical mapping cap=256/arg2 from R4/R7 history) so 8 blocks fit.
__global__ __launch_bounds__(256, 4)
void attn_kernel(const float* __restrict__ q_x,   // (B,T,64)
                 const float* __restrict__ kv_x,  // (B,T,127,64)
                 const float* __restrict__ Wk,    // (256,64)
                 const float* __restrict__ Wq,    // (256,64)
                 const float* __restrict__ Wv,    // (256,64)
                 const float* __restrict__ bias,  // (64,)
                 const float* __restrict__ Ws,    // (1,64)
                 const float* __restrict__ bs,    // (1,) -- cancels in softmax
                 float* __restrict__ out)         // (B,T,256)
{
    __shared__ __align__(16) _Float16 bh_lds[16][64][8]; // 16 KB fp16 B-frags, dead after scores
    __shared__ __align__(16) float qb_lds[128];          // this pair's query+bias per channel
    __shared__ __align__(16) float pp_lds[4][128];       // per-wave score partials

    // After the score phase bh_lds is dead: overlay probs + wkv partials on it.
    float* const probs = (float*)bh_lds;        // [2][128] probs per head
    float* const wkv2  = (float*)bh_lds + 256;  // [4][64]  per-wave wkv partials

    const int bt   = blockIdx.x & 1023;
    const int hp   = blockIdx.x >> 10;   // head-pair: global heads hp*2, hp*2+1
    const int tid  = threadIdx.x;
    const int wid  = tid >> 6;
    const int lane = tid & 63;
    const int col  = lane & 15;   // MFMA n/m lane index
    const int quad = lane >> 4;   // MFMA k-group / row-group
    const int h2   = wid & 1;     // head within pair
    const int role = wid >> 1;    // jt-half (scores) / n-half (Phase B)
    const int hg   = hp * 2 + h2; // global head

    const float* __restrict__ kvg = kv_x + (size_t)bt * NKEY * KDIM;

    // ---- stage kv (global) -> fragment-ordered fp16 LDS (4 chunks/wave) ----
    // chunk = nt*2+ks; write addr = chunk*1024 + lane*16: lane-linear, 0 conflicts.
    // Fragment content: kv[nt*16 + (lane&15)][ks*32 + (lane>>4)*8 + j]
    #pragma unroll
    for (int w = 0; w < 4; ++w) {
        const int chunk = w * 4 + wid;
        const int nt = chunk >> 1, ks = chunk & 1;
        const int n  = nt * 16 + col;
        const int k0 = ks * 32 + quad * 8;
        float4 a = make_float4(0.f, 0.f, 0.f, 0.f);
        float4 b = make_float4(0.f, 0.f, 0.f, 0.f);
        if (n < NKEY) {
            const float* p = kvg + (size_t)n * KDIM + k0;
            a = *(const float4*)p;
            b = *(const float4*)(p + 4);
        }
        *(half8*)&bh_lds[chunk][lane][0] = cvt8(a, b);
    }

    // ---- A-fragments: this wave's 32 Wk rows (j-half of head hg), fp16 RNE ----
    // lane holds Wk[hg*64 + role*32 + jtl*16 + col][ks*32 + quad*8 + j]
    half8 ah[2][2];
    #pragma unroll
    for (int jtl = 0; jtl < 2; ++jtl)
        #pragma unroll
        for (int ks = 0; ks < 2; ++ks) {
            const float* wrow = Wk + (size_t)(hg * 64 + role * 32 + jtl * 16 + col) * KDIM
                                   + ks * 32 + quad * 8;
            float4 a = *(const float4*)wrow;
            float4 b = *(const float4*)(wrow + 4);
            ah[jtl][ks] = cvt8(a, b);
        }

    // ---- query_j + bias for this pair's 128 channels (thread pairs split k) ----
    {
        const int c = tid >> 1, kh = tid & 1;
        const float4* Wq4 = (const float4*)(Wq + (size_t)(hp * 128 + c) * KDIM + kh * 32);
        const float4* q4g = (const float4*)(q_x + (size_t)bt * KDIM + kh * 32);
        float4 qa = make_float4(0.f, 0.f, 0.f, 0.f);
        #pragma unroll
        for (int i = 0; i < 8; ++i) {
            float4 w = Wq4[i];
            float4 q4 = q4g[i];
            qa.x = fmaf(q4.x, w.x, qa.x);
            qa.y = fmaf(q4.y, w.y, qa.y);
            qa.z = fmaf(q4.z, w.z, qa.z);
            qa.w = fmaf(q4.w, w.w, qa.w);
        }
        float r = (qa.x + qa.y) + (qa.z + qa.w);
        r += __shfl_xor(r, 1, 64);
        if (kh == 0) qb_lds[c] = r + bias[c & 63];
    }

    __syncthreads();   // B1: frags + qb ready

    // ---- qb folded into MFMA C-init; ws per-lane for epilogue ----
    // C/D layout: col = lane&15 = n, row = quad*4 + r = j within jtl-tile.
    floatx4 qb4[2];
    float4  wsv[2];
    #pragma unroll
    for (int jtl = 0; jtl < 2; ++jtl) {
        qb4[jtl] = *(const floatx4*)&qb_lds[h2 * 64 + role * 32 + jtl * 16 + quad * 4];
        wsv[jtl] = *(const float4*)&Ws[role * 32 + jtl * 16 + quad * 4];
    }

    // ---- scores: 8 n-tiles x 2 jtl x 2 ks single-pass fp16 MFMA ----
    #pragma unroll
    for (int nt = 0; nt < 8; ++nt) {
        half8 b0 = *(const half8*)&bh_lds[nt * 2 + 0][lane][0];
        half8 b1 = *(const half8*)&bh_lds[nt * 2 + 1][lane][0];
        float partial = 0.f;
        #pragma unroll
        for (int jtl = 0; jtl < 2; ++jtl) {
            floatx4 c = qb4[jtl];   // acc init = query+bias (keys add onto it)
            c = __builtin_amdgcn_mfma_f32_16x16x32_f16(ah[jtl][0], b0, c, 0, 0, 0);
            c = __builtin_amdgcn_mfma_f32_16x16x32_f16(ah[jtl][1], b1, c, 0, 0, 0);
            #pragma unroll
            for (int r = 0; r < 4; ++r)
                partial = fmaf(fast_tanh(c[r]), wsv[jtl][r], partial);
        }
        partial += __shfl_xor(partial, 16, 64);   // reduce across quads (same col)
        partial += __shfl_xor(partial, 32, 64);
        if (lane < 16) pp_lds[wid][nt * 16 + lane] = partial;
    }

    __syncthreads();   // B2: all partial scores written (bh_lds now dead)

    // ---- softmax over 127 real keys; wave pair sums its two j-half partials ----
    float invl;
    {
        float s_a = pp_lds[h2][lane]      + pp_lds[2 + h2][lane];
        float s_b = pp_lds[h2][64 + lane] + pp_lds[2 + h2][64 + lane];
        if (lane == 63) s_b = -1e30f;          // mask pad key 127
        float mx = fmaxf(s_a, s_b);
        #pragma unroll
        for (int off = 32; off > 0; off >>= 1)
            mx = fmaxf(mx, __shfl_xor(mx, off, 64));
        float pa = __expf(s_a - mx);
        float pb = __expf(s_b - mx);           // lane 63 -> 0
        float ls = pa + pb;
        #pragma unroll
        for (int off = 32; off > 0; off >>= 1)
            ls += __shfl_xor(ls, off, 64);
        invl = 1.f / ls;                       // both waves of the pair hold invl
        if (role == 0) {                       // one writer per head
            probs[h2 * 128 + lane]      = pa;  // unnormalized probs
            probs[h2 * 128 + 64 + lane] = pb;  // probs[h2*128+127] = 0 masks pad
        }
    }

    __syncthreads();   // B3: probs visible to the partner wave

    // ---- Phase B: wkv partial over this wave's 64-key half ----
    // kv column reads from global: consecutive lanes -> consecutive addrs,
    // L2/L3-hot (read during staging). Probs broadcast from LDS.
    {
        const float* kvl = kvg + lane;
        const float* pr  = probs + h2 * 128;
        const int n0 = role * 64;
        float w0 = 0.f, w1 = 0.f, w2 = 0.f, w3 = 0.f;
        #pragma unroll 4
        for (int n4 = n0; n4 < n0 + 64; n4 += 4) {
            float4 p4 = *(const float4*)&pr[n4];             // uniform broadcast
            const int n3 = (n4 + 3 < NKEY) ? (n4 + 3) : 0;   // p4.w==0 there
            w0 = fmaf(p4.x, kvl[(size_t)(n4 + 0) * KDIM], w0);
            w1 = fmaf(p4.y, kvl[(size_t)(n4 + 1) * KDIM], w1);
            w2 = fmaf(p4.z, kvl[(size_t)(n4 + 2) * KDIM], w2);
            w3 = fmaf(p4.w, kvl[(size_t)n3 * KDIM], w3);
        }
        wkv2[wid * 64 + lane] = ((w0 + w1) + (w2 + w3)) * invl;
    }

    __syncthreads();   // B4: wkv partials visible cross-wave

    // ---- Phase C: out[c] = (wkv_half0 + wkv_half1) . Wv[c,:] (pair-split k) ----
    {
        const int c = tid >> 1, kh = tid & 1;
        const int hc = c >> 6;                 // head-in-pair of channel c
        const float4* wa  = (const float4*)&wkv2[hc * 64 + kh * 32];
        const float4* wb  = (const float4*)&wkv2[(2 + hc) * 64 + kh * 32];
        const float4* Wv4 = (const float4*)(Wv + (size_t)(hp * 128 + c) * KDIM + kh * 32);
        float4 oa = make_float4(0.f, 0.f, 0.f, 0.f);
        #pragma unroll
        for (int i = 0; i < 8; ++i) {
            float4 w = Wv4[i];
            float4 v = wa[i];                  // broadcast reads
            float4 u = wb[i];
            oa.x = fmaf(v.x + u.x, w.x, oa.x);
            oa.y = fmaf(v.y + u.y, w.y, oa.y);
            oa.z = fmaf(v.z + u.z, w.z, oa.z);
            oa.w = fmaf(v.w + u.w, w.w, oa.w);
        }
        float r = (oa.x + oa.y) + (oa.z + oa.w);
        r += __shfl_xor(r, 1, 64);
        if (kh == 0) out[(size_t)bt * CH + hp * 128 + c] = r;
    }
}

extern "C" void kernel_launch(void* const* d_in, const int* in_sizes, int n_in,
                              void* d_out, int out_size, void* d_ws, size_t ws_size,
                              hipStream_t stream) {
    const float* q_x  = (const float*)d_in[0];
    const float* kv_x = (const float*)d_in[1];
    const float* Wk   = (const float*)d_in[2];
    const float* Wq   = (const float*)d_in[3];
    const float* Wv   = (const float*)d_in[4];
    const float* bias = (const float*)d_in[5];
    const float* Ws   = (const float*)d_in[6];
    const float* bs   = (const float*)d_in[7];
    float* out = (float*)d_out;

    // 2048 blocks: bt = bid & 1023, head-pair = bid >> 10.
    // The two blocks of one (b,t) are bid and bid+1024: same XCD under
    // round-robin (1024 % 8 == 0) and co-resident -> shared L2 for kv.
    attn_kernel<<<dim3(2 * B * T), dim3(256), 0, stream>>>(
        q_x, kv_x, Wk, Wq, Wv, bias, Ws, bs, out);
}

// Round 2
// 123.133 us; speedup vs baseline: 1.0040x; 1.0040x over previous
//
#include <hip/hip_runtime.h>
#include <math.h>

#define B 8
#define T 128
#define NKEY 127   // t-1
#define KDIM 64    // Q_DIM == KV_DIM
#define NH 4       // heads
#define CH 256     // NH*KDIM output channels

typedef _Float16 half8 __attribute__((ext_vector_type(8)));  // 8 fp16 (4 VGPRs)
typedef float floatx4 __attribute__((ext_vector_type(4)));   // MFMA C/D

// tanh(x) = 1 - 2/(e^{2x}+1). Saturates correctly at +/-inf, no clamp needed.
__device__ __forceinline__ float fast_tanh(float x) {
    float e = __expf(2.f * x);
    float r = __builtin_amdgcn_rcpf(e + 1.f);
    return fmaf(-2.f, r, 1.f);
}

// 8x float -> fp16 RNE. fp16 half-ulp 2^-11 on BOTH operands: verified in R9
// (absmax 4.88e-4, identical to the bf16 hi/lo 2-pass) at half the MFMA count.
__device__ __forceinline__ half8 cvt8(const float4& a, const float4& b) {
    half8 h;
    h[0] = (_Float16)a.x; h[1] = (_Float16)a.y;
    h[2] = (_Float16)a.z; h[3] = (_Float16)a.w;
    h[4] = (_Float16)b.x; h[5] = (_Float16)b.y;
    h[6] = (_Float16)b.z; h[7] = (_Float16)b.w;
    return h;
}

// R10: R9 post-mortem -- the head-pair block split DOUBLED kv staging (FETCH
// 25.5->34 MB) because every block must stage all 127 keys; staging is the
// dominant per-block cost, so dur rose 44->49us even though occupancy rose.
// Fix: keep ONE block per (b,t) (staging paid once, shared) and put R9's
// extra parallelism INSIDE the block: 512 threads = 8 waves.
//   wave wid: h = wid&3 (head), role = wid>>2
//     scores : wave computes j-half role*32..+31 of head h for all 8 n-tiles
//              (partials summed across the role pair through pp_lds)
//     Phase B: wave computes n-half role*64..+63 of head h
//   Wq / Phase C: 512 threads, channel = tid>>1, k-half = tid&1, pair-shfl.
// Occupancy cap: 1024 blocks x 8 waves / 256 CU = 32 waves/CU = 100%
// (R8 capped at 50%). LDS 21504 B -> 4 blocks/CU fits (86 KB).
// __launch_bounds__(512,8): 8 waves/SIMD -> VGPR cap 64 (R9 compiled at 48).
__global__ __launch_bounds__(512, 8)
void attn_kernel(const float* __restrict__ q_x,   // (B,T,64)
                 const float* __restrict__ kv_x,  // (B,T,127,64)
                 const float* __restrict__ Wk,    // (256,64)
                 const float* __restrict__ Wq,    // (256,64)
                 const float* __restrict__ Wv,    // (256,64)
                 const float* __restrict__ bias,  // (64,)
                 const float* __restrict__ Ws,    // (1,64)
                 const float* __restrict__ bs,    // (1,) -- cancels in softmax
                 float* __restrict__ out)         // (B,T,256)
{
    __shared__ __align__(16) _Float16 bh_lds[16][64][8]; // 16 KB fp16 B-frags, dead after scores
    __shared__ __align__(16) float qb_lds[CH];           // 1 KB: query+bias per channel
    __shared__ __align__(16) float pp_lds[8][128];       // 4 KB: per-wave score partials

    // After the score phase bh_lds is dead: overlay probs + wkv partials.
    float* const probs = (float*)bh_lds;        // [4][128] probs per head
    float* const wkv2  = (float*)bh_lds + 512;  // [8][64]  per-wave wkv partials

    const int bt   = blockIdx.x;
    const int tid  = threadIdx.x;
    const int wid  = tid >> 6;    // 0..7
    const int lane = tid & 63;
    const int col  = lane & 15;   // MFMA n/m lane index
    const int quad = lane >> 4;   // MFMA k-group / row-group
    const int h    = wid & 3;     // head
    const int role = wid >> 2;    // j-half (scores) / n-half (Phase B)

    const float* __restrict__ kvg = kv_x + (size_t)bt * NKEY * KDIM;

    // ---- stage kv (global) -> fragment-ordered fp16 LDS (2 chunks/wave) ----
    // chunk = nt*2+ks; write addr = chunk*1024 + lane*16: lane-linear, 0 conflicts.
    // Fragment content: kv[nt*16 + (lane&15)][ks*32 + (lane>>4)*8 + j]
    #pragma unroll
    for (int w = 0; w < 2; ++w) {
        const int chunk = w * 8 + wid;
        const int nt = chunk >> 1, ks = chunk & 1;
        const int n  = nt * 16 + col;
        const int k0 = ks * 32 + quad * 8;
        float4 a = make_float4(0.f, 0.f, 0.f, 0.f);
        float4 b = make_float4(0.f, 0.f, 0.f, 0.f);
        if (n < NKEY) {
            const float* p = kvg + (size_t)n * KDIM + k0;
            a = *(const float4*)p;
            b = *(const float4*)(p + 4);
        }
        *(half8*)&bh_lds[chunk][lane][0] = cvt8(a, b);
    }

    // ---- A-fragments: this wave's 32 Wk rows (j-half of head h), fp16 RNE ----
    // lane holds Wk[h*64 + role*32 + jtl*16 + col][ks*32 + quad*8 + j]
    half8 ah[2][2];
    #pragma unroll
    for (int jtl = 0; jtl < 2; ++jtl)
        #pragma unroll
        for (int ks = 0; ks < 2; ++ks) {
            const float* wrow = Wk + (size_t)(h * 64 + role * 32 + jtl * 16 + col) * KDIM
                                   + ks * 32 + quad * 8;
            float4 a = *(const float4*)wrow;
            float4 b = *(const float4*)(wrow + 4);
            ah[jtl][ks] = cvt8(a, b);
        }

    // ---- query_j + bias for all 256 channels (thread pairs split k) ----
    {
        const int c = tid >> 1, kh = tid & 1;
        const float4* Wq4 = (const float4*)(Wq + (size_t)c * KDIM + kh * 32);
        const float4* q4g = (const float4*)(q_x + (size_t)bt * KDIM + kh * 32);
        float4 qa = make_float4(0.f, 0.f, 0.f, 0.f);
        #pragma unroll
        for (int i = 0; i < 8; ++i) {
            float4 w = Wq4[i];
            float4 q4 = q4g[i];
            qa.x = fmaf(q4.x, w.x, qa.x);
            qa.y = fmaf(q4.y, w.y, qa.y);
            qa.z = fmaf(q4.z, w.z, qa.z);
            qa.w = fmaf(q4.w, w.w, qa.w);
        }
        float r = (qa.x + qa.y) + (qa.z + qa.w);
        r += __shfl_xor(r, 1, 64);
        if (kh == 0) qb_lds[c] = r + bias[c & 63];
    }

    __syncthreads();   // B1: frags + qb ready

    // ---- qb folded into MFMA C-init; ws per-lane for epilogue ----
    // C/D layout: col = lane&15 = n, row = quad*4 + r = j within jtl-tile.
    floatx4 qb4[2];
    float4  wsv[2];
    #pragma unroll
    for (int jtl = 0; jtl < 2; ++jtl) {
        qb4[jtl] = *(const floatx4*)&qb_lds[h * 64 + role * 32 + jtl * 16 + quad * 4];
        wsv[jtl] = *(const float4*)&Ws[role * 32 + jtl * 16 + quad * 4];
    }

    // ---- scores: 8 n-tiles x 2 jtl x 2 ks single-pass fp16 MFMA ----
    #pragma unroll
    for (int nt = 0; nt < 8; ++nt) {
        half8 b0 = *(const half8*)&bh_lds[nt * 2 + 0][lane][0];
        half8 b1 = *(const half8*)&bh_lds[nt * 2 + 1][lane][0];
        float partial = 0.f;
        #pragma unroll
        for (int jtl = 0; jtl < 2; ++jtl) {
            floatx4 c = qb4[jtl];   // acc init = query+bias (keys add onto it)
            c = __builtin_amdgcn_mfma_f32_16x16x32_f16(ah[jtl][0], b0, c, 0, 0, 0);
            c = __builtin_amdgcn_mfma_f32_16x16x32_f16(ah[jtl][1], b1, c, 0, 0, 0);
            #pragma unroll
            for (int r = 0; r < 4; ++r)
                partial = fmaf(fast_tanh(c[r]), wsv[jtl][r], partial);
        }
        partial += __shfl_xor(partial, 16, 64);   // reduce across quads (same col)
        partial += __shfl_xor(partial, 32, 64);
        if (lane < 16) pp_lds[wid][nt * 16 + lane] = partial;
    }

    __syncthreads();   // B2: all partial scores written (bh_lds now dead)

    // ---- softmax over 127 real keys; role pair's j-half partials summed ----
    float invl;
    {
        float s_a = pp_lds[h][lane]      + pp_lds[4 + h][lane];
        float s_b = pp_lds[h][64 + lane] + pp_lds[4 + h][64 + lane];
        if (lane == 63) s_b = -1e30f;          // mask pad key 127
        float mx = fmaxf(s_a, s_b);
        #pragma unroll
        for (int off = 32; off > 0; off >>= 1)
            mx = fmaxf(mx, __shfl_xor(mx, off, 64));
        float pa = __expf(s_a - mx);
        float pb = __expf(s_b - mx);           // lane 63 -> 0
        float ls = pa + pb;
        #pragma unroll
        for (int off = 32; off > 0; off >>= 1)
            ls += __shfl_xor(ls, off, 64);
        invl = 1.f / ls;                       // both role-waves hold invl
        if (role == 0) {                       // one writer per head
            probs[h * 128 + lane]      = pa;   // unnormalized probs
            probs[h * 128 + 64 + lane] = pb;   // probs[h*128+127] = 0 masks pad
        }
    }

    __syncthreads();   // B3: probs visible to partner waves

    // ---- Phase B: wkv partial over this wave's 64-key half ----
    // kv column reads from global: consecutive lanes -> consecutive addrs,
    // L2/L3-hot (read during staging). Probs broadcast from LDS.
    {
        const float* kvl = kvg + lane;
        const float* pr  = probs + h * 128;
        const int n0 = role * 64;
        float w0 = 0.f, w1 = 0.f, w2 = 0.f, w3 = 0.f;
        #pragma unroll 4
        for (int n4 = n0; n4 < n0 + 64; n4 += 4) {
            float4 p4 = *(const float4*)&pr[n4];             // uniform broadcast
            const int n3 = (n4 + 3 < NKEY) ? (n4 + 3) : 0;   // p4.w==0 there
            w0 = fmaf(p4.x, kvl[(size_t)(n4 + 0) * KDIM], w0);
            w1 = fmaf(p4.y, kvl[(size_t)(n4 + 1) * KDIM], w1);
            w2 = fmaf(p4.z, kvl[(size_t)(n4 + 2) * KDIM], w2);
            w3 = fmaf(p4.w, kvl[(size_t)n3 * KDIM], w3);
        }
        wkv2[wid * 64 + lane] = ((w0 + w1) + (w2 + w3)) * invl;
    }

    __syncthreads();   // B4: wkv partials visible cross-wave

    // ---- Phase C: out[c] = (wkv_half0 + wkv_half1) . Wv[c,:] (pair-split k) ----
    {
        const int c = tid >> 1, kh = tid & 1;
        const int hc = c >> 6;                 // head of channel c
        const float4* wa  = (const float4*)&wkv2[hc * 64 + kh * 32];
        const float4* wb  = (const float4*)&wkv2[(4 + hc) * 64 + kh * 32];
        const float4* Wv4 = (const float4*)(Wv + (size_t)c * KDIM + kh * 32);
        float4 oa = make_float4(0.f, 0.f, 0.f, 0.f);
        #pragma unroll
        for (int i = 0; i < 8; ++i) {
            float4 w = Wv4[i];
            float4 v = wa[i];                  // broadcast reads
            float4 u = wb[i];
            oa.x = fmaf(v.x + u.x, w.x, oa.x);
            oa.y = fmaf(v.y + u.y, w.y, oa.y);
            oa.z = fmaf(v.z + u.z, w.z, oa.z);
            oa.w = fmaf(v.w + u.w, w.w, oa.w);
        }
        float r = (oa.x + oa.y) + (oa.z + oa.w);
        r += __shfl_xor(r, 1, 64);
        if (kh == 0) out[(size_t)bt * CH + c] = r;
    }
}

extern "C" void kernel_launch(void* const* d_in, const int* in_sizes, int n_in,
                              void* d_out, int out_size, void* d_ws, size_t ws_size,
                              hipStream_t stream) {
    const float* q_x  = (const float*)d_in[0];
    const float* kv_x = (const float*)d_in[1];
    const float* Wk   = (const float*)d_in[2];
    const float* Wq   = (const float*)d_in[3];
    const float* Wv   = (const float*)d_in[4];
    const float* bias = (const float*)d_in[5];
    const float* Ws   = (const float*)d_in[6];
    const float* bs   = (const float*)d_in[7];
    float* out = (float*)d_out;

    attn_kernel<<<dim3(B * T), dim3(512), 0, stream>>>(
        q_x, kv_x, Wk, Wq, Wv, bias, Ws, bs, out);
}